// Round 1
// baseline (740.687 us; speedup 1.0000x reference)
//
#include <hip/hip_runtime.h>
#include <cstddef>

// Problem constants (match reference)
#define B_ 4
#define S_ 1024
#define E_ 512
#define H_ 8
#define F_ 2048
// DK = 64, scale = 1/8

// ---------------------------------------------------------------------------
// GEMM: C[M,N] = act(A[M,K] @ W[K,N] + bias[N]);  act: 0=none, 1=exact GELU
// 64x64 block tile, BK=16, 256 threads, 4x4 per thread, fp32.
// ---------------------------------------------------------------------------
__global__ __launch_bounds__(256) void gemm_kernel(
    const float* __restrict__ A, const float* __restrict__ W,
    const float* __restrict__ bias, float* __restrict__ C,
    int M, int N, int K, int act)
{
  // +4 pad keeps 16B alignment for float4 LDS stores and breaks pow-2 strides
  __shared__ __align__(16) float As[16][68];  // [k][m]
  __shared__ __align__(16) float Bs[16][68];  // [k][n]

  const int tid = threadIdx.x;
  const int tx = tid & 15, ty = tid >> 4;
  const int bm = blockIdx.y * 64, bn = blockIdx.x * 64;

  // A-tile load map: each thread one float4; 64 rows x 16 cols
  const int arow = tid >> 2;          // 0..63
  const int acol = (tid & 3) * 4;     // 0,4,8,12
  // B-tile load map: 16 rows x 64 cols
  const int brow = tid >> 4;          // 0..15
  const int bcol = (tid & 15) * 4;    // 0..60

  float acc[4][4] = {};

  for (int k0 = 0; k0 < K; k0 += 16) {
    const float4 a4 = *(const float4*)&A[(size_t)(bm + arow) * K + (k0 + acol)];
    const float4 b4 = *(const float4*)&W[(size_t)(k0 + brow) * N + (bn + bcol)];
    As[acol + 0][arow] = a4.x;
    As[acol + 1][arow] = a4.y;
    As[acol + 2][arow] = a4.z;
    As[acol + 3][arow] = a4.w;
    *(float4*)&Bs[brow][bcol] = b4;
    __syncthreads();

    #pragma unroll
    for (int kk = 0; kk < 16; ++kk) {
      float av[4], bv[4];
      #pragma unroll
      for (int i = 0; i < 4; ++i) av[i] = As[kk][ty * 4 + i];
      #pragma unroll
      for (int j = 0; j < 4; ++j) bv[j] = Bs[kk][tx * 4 + j];
      #pragma unroll
      for (int i = 0; i < 4; ++i)
        #pragma unroll
        for (int j = 0; j < 4; ++j)
          acc[i][j] += av[i] * bv[j];
    }
    __syncthreads();
  }

  const float4 bias4 = *(const float4*)&bias[bn + tx * 4];
  const float bb[4] = {bias4.x, bias4.y, bias4.z, bias4.w};
  #pragma unroll
  for (int i = 0; i < 4; ++i) {
    float4 ov;
    float* po = (float*)&ov;
    #pragma unroll
    for (int j = 0; j < 4; ++j) {
      float v = acc[i][j] + bb[j];
      if (act == 1) v = 0.5f * v * (1.0f + erff(v * 0.70710678118654752f));
      po[j] = v;
    }
    *(float4*)&C[(size_t)(bm + ty * 4 + i) * N + bn + tx * 4] = ov;
  }
}

// ---------------------------------------------------------------------------
// Flash-style attention with additive bias. One block = 64 q-rows of one
// (batch, head). K tiles of 64. Q/K/V/P staged in LDS. fp32.
// ctx[b,q,h,d] = sum_k softmax_k(q.k/8 + bias[b,h,q,k]) * v[k]
// ---------------------------------------------------------------------------
__global__ __launch_bounds__(256) void attn_kernel(
    const float* __restrict__ Q, const float* __restrict__ KV,
    const float* __restrict__ bias, float* __restrict__ Ctx)
{
  __shared__ float Qs[64][65];  // [m][d]
  __shared__ float Ks[64][65];  // [n][d]
  __shared__ float Vs[64][65];  // [n][d]
  __shared__ float Ps[64][65];  // [m][n]

  const int tid = threadIdx.x;
  const int tx = tid & 15, ty = tid >> 4;
  const int qt = blockIdx.x;   // q tile (0..15)
  const int h  = blockIdx.y;   // head
  const int b  = blockIdx.z;   // batch
  const float scale = 0.125f;  // 1/sqrt(64)

  // Load Q tile: 64x64, one float4 x 4 passes per thread
  {
    const int r0 = tid >> 4;            // 0..15
    const int c4 = (tid & 15) * 4;      // 0..60
    #pragma unroll
    for (int p = 0; p < 4; ++p) {
      const int r = r0 + p * 16;
      const float4 v = *(const float4*)&Q[((size_t)(b * S_ + qt * 64 + r)) * E_ + h * 64 + c4];
      Qs[r][c4 + 0] = v.x; Qs[r][c4 + 1] = v.y;
      Qs[r][c4 + 2] = v.z; Qs[r][c4 + 3] = v.w;
    }
  }

  float o[4][4] = {};
  float mstate[4], lstate[4];
  #pragma unroll
  for (int i = 0; i < 4; ++i) { mstate[i] = -1e30f; lstate[i] = 0.f; }

  for (int kb = 0; kb < S_ / 64; ++kb) {
    __syncthreads();  // previous iteration's PV reads of Ps/Vs are done
    {
      const int r0 = tid >> 4;
      const int c4 = (tid & 15) * 4;
      #pragma unroll
      for (int p = 0; p < 4; ++p) {
        const int r = r0 + p * 16;
        const float4 v = *(const float4*)&KV[((size_t)(b * S_ + kb * 64 + r)) * E_ + h * 64 + c4];
        Ks[r][c4 + 0] = v.x; Ks[r][c4 + 1] = v.y;
        Ks[r][c4 + 2] = v.z; Ks[r][c4 + 3] = v.w;
        Vs[r][c4 + 0] = v.x; Vs[r][c4 + 1] = v.y;
        Vs[r][c4 + 2] = v.z; Vs[r][c4 + 3] = v.w;
      }
    }
    __syncthreads();

    // S tile: s[i][j] = sum_d Qs[m][d] * Ks[n][d]
    float s[4][4] = {};
    #pragma unroll 4
    for (int d = 0; d < 64; ++d) {
      float qv[4], kv4[4];
      #pragma unroll
      for (int i = 0; i < 4; ++i) qv[i] = Qs[ty * 4 + i][d];
      #pragma unroll
      for (int j = 0; j < 4; ++j) kv4[j] = Ks[tx * 4 + j][d];
      #pragma unroll
      for (int i = 0; i < 4; ++i)
        #pragma unroll
        for (int j = 0; j < 4; ++j)
          s[i][j] += qv[i] * kv4[j];
    }

    // scale + bias
    #pragma unroll
    for (int i = 0; i < 4; ++i) {
      const size_t brow = (((size_t)(b * H_ + h)) * S_ + (qt * 64 + ty * 4 + i)) * S_
                        + kb * 64 + tx * 4;
      const float4 bv = *(const float4*)&bias[brow];
      s[i][0] = s[i][0] * scale + bv.x;
      s[i][1] = s[i][1] * scale + bv.y;
      s[i][2] = s[i][2] * scale + bv.z;
      s[i][3] = s[i][3] * scale + bv.w;
    }

    // online softmax (row = 16 lanes in tx direction; xor masks 1,2,4,8
    // permute only the low-4 lane bits -> stays inside the row group)
    #pragma unroll
    for (int i = 0; i < 4; ++i) {
      float rm = fmaxf(fmaxf(s[i][0], s[i][1]), fmaxf(s[i][2], s[i][3]));
      rm = fmaxf(rm, __shfl_xor(rm, 1));
      rm = fmaxf(rm, __shfl_xor(rm, 2));
      rm = fmaxf(rm, __shfl_xor(rm, 4));
      rm = fmaxf(rm, __shfl_xor(rm, 8));
      const float mnew = fmaxf(mstate[i], rm);
      const float alpha = __expf(mstate[i] - mnew);
      mstate[i] = mnew;
      float rs = 0.f;
      #pragma unroll
      for (int j = 0; j < 4; ++j) { s[i][j] = __expf(s[i][j] - mnew); rs += s[i][j]; }
      rs += __shfl_xor(rs, 1);
      rs += __shfl_xor(rs, 2);
      rs += __shfl_xor(rs, 4);
      rs += __shfl_xor(rs, 8);
      lstate[i] = lstate[i] * alpha + rs;
      #pragma unroll
      for (int j = 0; j < 4; ++j) o[i][j] *= alpha;
      #pragma unroll
      for (int j = 0; j < 4; ++j) Ps[ty * 4 + i][tx * 4 + j] = s[i][j];
    }
    __syncthreads();

    // PV: o[m][d] += sum_n Ps[m][n] * Vs[n][d]
    #pragma unroll 4
    for (int n = 0; n < 64; ++n) {
      float pv[4], vv[4];
      #pragma unroll
      for (int i = 0; i < 4; ++i) pv[i] = Ps[ty * 4 + i][n];
      #pragma unroll
      for (int j = 0; j < 4; ++j) vv[j] = Vs[n][tx * 4 + j];
      #pragma unroll
      for (int i = 0; i < 4; ++i)
        #pragma unroll
        for (int j = 0; j < 4; ++j)
          o[i][j] += pv[i] * vv[j];
    }
  }

  #pragma unroll
  for (int i = 0; i < 4; ++i) {
    const float inv = 1.0f / lstate[i];
    float4 ov;
    ov.x = o[i][0] * inv; ov.y = o[i][1] * inv;
    ov.z = o[i][2] * inv; ov.w = o[i][3] * inv;
    *(float4*)&Ctx[((size_t)(b * S_ + qt * 64 + ty * 4 + i)) * E_ + h * 64 + tx * 4] = ov;
  }
}

// ---------------------------------------------------------------------------
// out[row] = xin[row] + LayerNorm(y[row]) * g + beta ; row length E_=512.
// One block (256 threads) per row; 2 floats/thread.
// ---------------------------------------------------------------------------
__global__ __launch_bounds__(256) void add_ln_kernel(
    const float* __restrict__ xin, const float* __restrict__ y,
    const float* __restrict__ g, const float* __restrict__ beta,
    float* __restrict__ out)
{
  const int row = blockIdx.x;
  const int tid = threadIdx.x;
  const size_t base = (size_t)row * E_;

  const float2 v = *(const float2*)&y[base + tid * 2];
  float sum = v.x + v.y;
  float sq  = v.x * v.x + v.y * v.y;
  #pragma unroll
  for (int m = 32; m >= 1; m >>= 1) {
    sum += __shfl_xor(sum, m);
    sq  += __shfl_xor(sq, m);
  }
  __shared__ float rs[4], rq[4];
  const int wid = tid >> 6, lane = tid & 63;
  if (lane == 0) { rs[wid] = sum; rq[wid] = sq; }
  __syncthreads();
  sum = rs[0] + rs[1] + rs[2] + rs[3];
  sq  = rq[0] + rq[1] + rq[2] + rq[3];

  const float mu   = sum * (1.0f / E_);
  const float var  = sq * (1.0f / E_) - mu * mu;
  const float rstd = rsqrtf(var + 1e-5f);

  const float2 xv = *(const float2*)&xin[base + tid * 2];
  const float2 gv = *(const float2*)&g[tid * 2];
  const float2 bv = *(const float2*)&beta[tid * 2];
  float2 ov;
  ov.x = xv.x + (v.x - mu) * rstd * gv.x + bv.x;
  ov.y = xv.y + (v.y - mu) * rstd * gv.y + bv.y;
  *(float2*)&out[base + tid * 2] = ov;
}

// ---------------------------------------------------------------------------
extern "C" void kernel_launch(void* const* d_in, const int* in_sizes, int n_in,
                              void* d_out, int out_size, void* d_ws, size_t ws_size,
                              hipStream_t stream)
{
  const float* x   = (const float*)d_in[0];
  const float* bia = (const float*)d_in[1];
  const float* Wq  = (const float*)d_in[2];
  const float* bq  = (const float*)d_in[3];
  const float* Wv  = (const float*)d_in[4];
  const float* bv  = (const float*)d_in[5];
  const float* Wo  = (const float*)d_in[6];
  const float* bo  = (const float*)d_in[7];
  const float* W1  = (const float*)d_in[8];
  const float* b1  = (const float*)d_in[9];
  const float* W2  = (const float*)d_in[10];
  const float* b2  = (const float*)d_in[11];
  const float* g1  = (const float*)d_in[12];
  const float* be1 = (const float*)d_in[13];
  const float* g2  = (const float*)d_in[14];
  const float* be2 = (const float*)d_in[15];
  float* out = (float*)d_out;
  float* ws  = (float*)d_ws;

  const int NT = B_ * S_;                 // 4096 token rows
  const size_t SZ = (size_t)NT * E_;      // 2,097,152 floats

  // workspace layout (floats):
  //  [0,SZ) q | [SZ,2SZ) kv | [2SZ,3SZ) ctx | [3SZ,4SZ) y | [4SZ,5SZ) x1
  //  h (NT*F = 4*SZ) reuses [0,4SZ) after x1 is built | [5SZ,6SZ) y2
  float* q   = ws;
  float* kv  = ws + SZ;
  float* ctx = ws + 2 * SZ;
  float* y   = ws + 3 * SZ;
  float* x1  = ws + 4 * SZ;
  float* h   = ws;            // overwrites q/kv/ctx/y (dead by then)
  float* y2  = ws + 5 * SZ;

  const dim3 blk(256);

  // q = x@Wq+bq ; kv = x@Wv+bv (k and v are identical in the reference)
  gemm_kernel<<<dim3(E_ / 64, NT / 64), blk, 0, stream>>>(x, Wq, bq, q,  NT, E_, E_, 0);
  gemm_kernel<<<dim3(E_ / 64, NT / 64), blk, 0, stream>>>(x, Wv, bv, kv, NT, E_, E_, 0);

  // ctx = softmax(q kv^T/8 + bias) @ kv
  attn_kernel<<<dim3(S_ / 64, H_, B_), blk, 0, stream>>>(q, kv, bia, ctx);

  // y = ctx@Wo+bo ; x1 = x + LN(y)
  gemm_kernel<<<dim3(E_ / 64, NT / 64), blk, 0, stream>>>(ctx, Wo, bo, y, NT, E_, E_, 0);
  add_ln_kernel<<<dim3(NT), blk, 0, stream>>>(x, y, g1, be1, x1);

  // h = gelu(x1@W1+b1) ; y2 = h@W2+b2 ; out = x1 + LN(y2)
  gemm_kernel<<<dim3(F_ / 64, NT / 64), blk, 0, stream>>>(x1, W1, b1, h, NT, F_, E_, 1);
  gemm_kernel<<<dim3(E_ / 64, NT / 64), blk, 0, stream>>>(h, W2, b2, y2, NT, E_, F_, 0);
  add_ln_kernel<<<dim3(NT), blk, 0, stream>>>(x1, y2, g2, be2, out);
}

// Round 3
// 410.439 us; speedup vs baseline: 1.8046x; 1.8046x over previous
//
#include <hip/hip_runtime.h>
#include <cstddef>
#include <cstdint>

#define B_ 4
#define S_ 1024
#define E_ 512
#define H_ 8
#define F_ 2048
// DK=64, scale=1/8

typedef __attribute__((ext_vector_type(8))) short s16x8;
typedef __attribute__((ext_vector_type(4))) short s16x4;
typedef __attribute__((ext_vector_type(4))) float f32x4;

static __device__ __forceinline__ short f2bf(float f) {
  union { float f; unsigned u; } x; x.f = f;
  unsigned r = x.u + 0x7fffu + ((x.u >> 16) & 1u);   // RNE
  return (short)(r >> 16);
}

static __device__ __forceinline__ void gload_lds16(const void* g, void* l) {
  __builtin_amdgcn_global_load_lds(
      (const __attribute__((address_space(1))) void*)g,
      (__attribute__((address_space(3))) void*)l, 16, 0, 0);
}

// ---------------------------------------------------------------------------
// convert fp32 -> bf16 (vectorized), n % 4 == 0
// ---------------------------------------------------------------------------
__global__ __launch_bounds__(256) void f2b_kernel(const float* __restrict__ in,
                                                  short* __restrict__ out, int n) {
  int i = (blockIdx.x * 256 + threadIdx.x) * 4;
  if (i >= n) return;
  const float4 v = *(const float4*)&in[i];
  s16x4 o = { f2bf(v.x), f2bf(v.y), f2bf(v.z), f2bf(v.w) };
  *(s16x4*)&out[i] = o;
}

// ---------------------------------------------------------------------------
// W [K][N] fp32  ->  Wt [N][K] bf16.  K,N multiples of 32.
// ---------------------------------------------------------------------------
__global__ __launch_bounds__(256) void transpose_b_kernel(const float* __restrict__ in,
                                                          short* __restrict__ out,
                                                          int K, int N) {
  __shared__ float tile[32][33];
  const int bx = blockIdx.x * 32;   // N dim
  const int by = blockIdx.y * 32;   // K dim
  const int tx = threadIdx.x & 31, ty = threadIdx.x >> 5;  // 32 x 8
  #pragma unroll
  for (int i = ty; i < 32; i += 8)
    tile[i][tx] = in[(size_t)(by + i) * N + bx + tx];
  __syncthreads();
  #pragma unroll
  for (int i = ty; i < 32; i += 8)
    out[(size_t)(bx + i) * K + by + tx] = f2bf(tile[tx][i]);
}

// ---------------------------------------------------------------------------
// MFMA GEMM (m97 structure): C[M,N] = act(A[M,K] @ B[K,N] + bias)
// A: bf16 [M][K] row-major.  Bt: bf16 [N][K] row-major (B transposed).
// 128x128 tile, BK=32, 256 threads (4 waves, 2x2), global_load_lds staging.
// act: 0 none, 1 exact GELU.  Output: Cf (fp32) if non-null else Cb (bf16).
// ---------------------------------------------------------------------------
__global__ __launch_bounds__(256) void mfma_gemm_kernel(
    const short* __restrict__ A, const short* __restrict__ Bt,
    const float* __restrict__ bias, float* __restrict__ Cf,
    short* __restrict__ Cb, int M, int N, int K, int act)
{
  __shared__ __align__(16) short As[128 * 32];
  __shared__ __align__(16) short Bs[128 * 32];

  const int t = threadIdx.x;
  const int w = t >> 6, lane = t & 63;
  const int wr = w >> 1, wc = w & 1;
  const int lr = lane & 15, lg = lane >> 4;
  const int bm = blockIdx.y * 128, bn = blockIdx.x * 128;

  // staging map: issue i covers rows i*64 + t/4, kcol (t%4)*8
  const int srow = t >> 2;
  const int skcol = (t & 3) * 8;

  f32x4 acc[4][4];
  #pragma unroll
  for (int m = 0; m < 4; ++m)
    #pragma unroll
    for (int n = 0; n < 4; ++n) acc[m][n] = (f32x4){0.f, 0.f, 0.f, 0.f};

  for (int k0 = 0; k0 < K; k0 += 32) {
    // stage A,B tiles: 4 x global_load_lds_dwordx4
    gload_lds16(&A[(size_t)(bm + srow) * K + k0 + skcol],        &As[t * 8]);
    gload_lds16(&A[(size_t)(bm + 64 + srow) * K + k0 + skcol],   &As[2048 + t * 8]);
    gload_lds16(&Bt[(size_t)(bn + srow) * K + k0 + skcol],       &Bs[t * 8]);
    gload_lds16(&Bt[(size_t)(bn + 64 + srow) * K + k0 + skcol],  &Bs[2048 + t * 8]);
    __syncthreads();   // drains vmcnt(0): tiles resident

    s16x8 af[4], bf[4];
    #pragma unroll
    for (int m = 0; m < 4; ++m)
      af[m] = *(const s16x8*)&As[(wr * 64 + m * 16 + lr) * 32 + lg * 8];
    #pragma unroll
    for (int n = 0; n < 4; ++n)
      bf[n] = *(const s16x8*)&Bs[(wc * 64 + n * 16 + lr) * 32 + lg * 8];
    #pragma unroll
    for (int m = 0; m < 4; ++m)
      #pragma unroll
      for (int n = 0; n < 4; ++n)
        acc[m][n] = __builtin_amdgcn_mfma_f32_16x16x32_bf16(af[m], bf[n], acc[m][n], 0, 0, 0);
    __syncthreads();   // frag reads done before next stage overwrites
  }

  // epilogue: C/D layout col=lane&15, row=(lane>>4)*4+r  [m89]
  #pragma unroll
  for (int m = 0; m < 4; ++m) {
    #pragma unroll
    for (int n = 0; n < 4; ++n) {
      const int col = bn + wc * 64 + n * 16 + lr;
      const float bb = bias[col];
      #pragma unroll
      for (int r = 0; r < 4; ++r) {
        const int row = bm + wr * 64 + m * 16 + lg * 4 + r;
        float v = acc[m][n][r] + bb;
        if (act == 1) v = 0.5f * v * (1.0f + erff(v * 0.70710678118654752f));
        if (Cf) Cf[(size_t)row * N + col] = v;
        else    Cb[(size_t)row * N + col] = f2bf(v);
      }
    }
  }
}

// ---------------------------------------------------------------------------
// MFMA flash attention with additive bias.
// Q,KV: bf16 [B*S][E] (token-major, head h at cols h*64..).  bias fp32.
// Block: 256 thr = 4 waves; q-tile 64 rows (wave w: rows w*16), kv-tiles of 64.
// ctx out bf16.
// ---------------------------------------------------------------------------
__global__ __launch_bounds__(256) void attn_mfma_kernel(
    const short* __restrict__ Q, const short* __restrict__ KV,
    const float* __restrict__ bias, short* __restrict__ Ctx)
{
  __shared__ __align__(16) short Vt[64 * 68];       // [d][kv], stride 68 (8B rows)
  __shared__ __align__(16) short Pb[4][16 * 72];    // per-wave P [q16][kv64], stride 72 (16B rows)

  const int t = threadIdx.x;
  const int w = t >> 6, lane = t & 63;
  const int lr = lane & 15, lg = lane >> 4;
  const int qt = blockIdx.x, h = blockIdx.y, b = blockIdx.z;

  // Q A-fragments (rows = q, k = d), direct from global (16B aligned)
  s16x8 aq[2];
  {
    const size_t qoff = (size_t)(b * S_ + qt * 64 + w * 16 + lr) * E_ + h * 64;
    aq[0] = *(const s16x8*)&Q[qoff + lg * 8];
    aq[1] = *(const s16x8*)&Q[qoff + 32 + lg * 8];
  }

  f32x4 o[4];
  #pragma unroll
  for (int n = 0; n < 4; ++n) o[n] = (f32x4){0.f, 0.f, 0.f, 0.f};
  float mst[4] = {-1e30f, -1e30f, -1e30f, -1e30f};
  float lst[4] = {0.f, 0.f, 0.f, 0.f};

  const int kv_r = t & 63;          // V-stage: row of V tile
  const int d0 = (t >> 6) * 16;     // V-stage: 16 d-cols per thread

  for (int kb = 0; kb < S_ / 64; ++kb) {
    // V chunk -> regs (transposed store after barrier)
    const size_t voff = (size_t)(b * S_ + kb * 64 + kv_r) * E_ + h * 64 + d0;
    const s16x8 v0 = *(const s16x8*)&KV[voff];
    const s16x8 v1 = *(const s16x8*)&KV[voff + 8];

    // K B-fragments direct from global: col = kv, k = d (contiguous)
    s16x8 bk[4][2];
    #pragma unroll
    for (int n = 0; n < 4; ++n) {
      const size_t koff = (size_t)(b * S_ + kb * 64 + n * 16 + lr) * E_ + h * 64;
      bk[n][0] = *(const s16x8*)&KV[koff + lg * 8];
      bk[n][1] = *(const s16x8*)&KV[koff + 32 + lg * 8];
    }

    __syncthreads();   // previous iteration's Vt/Pb reads complete

    #pragma unroll
    for (int i = 0; i < 8; ++i) Vt[(d0 + i) * 68 + kv_r] = v0[i];
    #pragma unroll
    for (int i = 0; i < 8; ++i) Vt[(d0 + 8 + i) * 68 + kv_r] = v1[i];

    // S = Q K^T
    f32x4 c[4];
    #pragma unroll
    for (int n = 0; n < 4; ++n) c[n] = (f32x4){0.f, 0.f, 0.f, 0.f};
    #pragma unroll
    for (int ks = 0; ks < 2; ++ks)
      #pragma unroll
      for (int n = 0; n < 4; ++n)
        c[n] = __builtin_amdgcn_mfma_f32_16x16x32_bf16(aq[ks], bk[n][ks], c[n], 0, 0, 0);

    // scale + bias (C layout: col=kv=n*16+lr, row=q=lg*4+r)
    float p[4][4];   // [n][r]
    #pragma unroll
    for (int r = 0; r < 4; ++r) {
      const int qrow = qt * 64 + w * 16 + lg * 4 + r;
      const size_t boff = (((size_t)(b * H_ + h)) * S_ + qrow) * S_ + kb * 64 + lr;
      #pragma unroll
      for (int n = 0; n < 4; ++n)
        p[n][r] = c[n][r] * 0.125f + bias[boff + n * 16];
    }

    // online softmax per q-row (row lives in 16 lanes lr=0..15)
    #pragma unroll
    for (int r = 0; r < 4; ++r) {
      float rm = fmaxf(fmaxf(p[0][r], p[1][r]), fmaxf(p[2][r], p[3][r]));
      rm = fmaxf(rm, __shfl_xor(rm, 1));
      rm = fmaxf(rm, __shfl_xor(rm, 2));
      rm = fmaxf(rm, __shfl_xor(rm, 4));
      rm = fmaxf(rm, __shfl_xor(rm, 8));
      const float mnew = fmaxf(mst[r], rm);
      const float alpha = __expf(mst[r] - mnew);
      mst[r] = mnew;
      float rs = 0.f;
      #pragma unroll
      for (int n = 0; n < 4; ++n) { p[n][r] = __expf(p[n][r] - mnew); rs += p[n][r]; }
      rs += __shfl_xor(rs, 1);
      rs += __shfl_xor(rs, 2);
      rs += __shfl_xor(rs, 4);
      rs += __shfl_xor(rs, 8);
      lst[r] = lst[r] * alpha + rs;
      #pragma unroll
      for (int n = 0; n < 4; ++n) o[n][r] *= alpha;
    }

    // P -> bf16 in per-wave LDS ([q][kv], stride 72)
    #pragma unroll
    for (int r = 0; r < 4; ++r)
      #pragma unroll
      for (int n = 0; n < 4; ++n)
        Pb[w][(lg * 4 + r) * 72 + n * 16 + lr] = f2bf(p[n][r]);

    __syncthreads();   // Vt + Pb visible

    // PV: A = P (k=kv), B = V (k=kv, n=d) from Vt
    s16x8 pa[2];
    pa[0] = *(const s16x8*)&Pb[w][lr * 72 + lg * 8];
    pa[1] = *(const s16x8*)&Pb[w][lr * 72 + 32 + lg * 8];
    #pragma unroll
    for (int ks = 0; ks < 2; ++ks) {
      #pragma unroll
      for (int n = 0; n < 4; ++n) {
        const int off = (n * 16 + lr) * 68 + ks * 32 + lg * 8;
        const s16x4 lo = *(const s16x4*)&Vt[off];
        const s16x4 hi = *(const s16x4*)&Vt[off + 4];
        const s16x8 bv = {lo[0], lo[1], lo[2], lo[3], hi[0], hi[1], hi[2], hi[3]};
        o[n] = __builtin_amdgcn_mfma_f32_16x16x32_bf16(pa[ks], bv, o[n], 0, 0, 0);
      }
    }
  }

  // epilogue: ctx bf16
  #pragma unroll
  for (int r = 0; r < 4; ++r) {
    const int qrow = qt * 64 + w * 16 + lg * 4 + r;
    const float inv = 1.0f / lst[r];
    #pragma unroll
    for (int n = 0; n < 4; ++n)
      Ctx[(size_t)(b * S_ + qrow) * E_ + h * 64 + n * 16 + lr] = f2bf(o[n][r] * inv);
  }
}

// ---------------------------------------------------------------------------
// out = xin + LayerNorm(y)*g + beta ; optional bf16 copy of out.
// ---------------------------------------------------------------------------
__global__ __launch_bounds__(256) void add_ln_kernel(
    const float* __restrict__ xin, const float* __restrict__ y,
    const float* __restrict__ g, const float* __restrict__ beta,
    float* __restrict__ out, short* __restrict__ outb)
{
  const int row = blockIdx.x;
  const int tid = threadIdx.x;
  const size_t base = (size_t)row * E_;

  const float2 v = *(const float2*)&y[base + tid * 2];
  float sum = v.x + v.y;
  float sq  = v.x * v.x + v.y * v.y;
  #pragma unroll
  for (int m = 32; m >= 1; m >>= 1) {
    sum += __shfl_xor(sum, m);
    sq  += __shfl_xor(sq, m);
  }
  __shared__ float rs[4], rq[4];
  const int wid = tid >> 6, lane = tid & 63;
  if (lane == 0) { rs[wid] = sum; rq[wid] = sq; }
  __syncthreads();
  sum = rs[0] + rs[1] + rs[2] + rs[3];
  sq  = rq[0] + rq[1] + rq[2] + rq[3];

  const float mu   = sum * (1.0f / E_);
  const float var  = sq * (1.0f / E_) - mu * mu;
  const float rstd = rsqrtf(var + 1e-5f);

  const float2 xv = *(const float2*)&xin[base + tid * 2];
  const float2 gv = *(const float2*)&g[tid * 2];
  const float2 bv = *(const float2*)&beta[tid * 2];
  float2 ov;
  ov.x = xv.x + (v.x - mu) * rstd * gv.x + bv.x;
  ov.y = xv.y + (v.y - mu) * rstd * gv.y + bv.y;
  *(float2*)&out[base + tid * 2] = ov;
  if (outb) {
    outb[base + tid * 2]     = f2bf(ov.x);
    outb[base + tid * 2 + 1] = f2bf(ov.y);
  }
}

// ---------------------------------------------------------------------------
extern "C" void kernel_launch(void* const* d_in, const int* in_sizes, int n_in,
                              void* d_out, int out_size, void* d_ws, size_t ws_size,
                              hipStream_t stream)
{
  const float* x   = (const float*)d_in[0];
  const float* bia = (const float*)d_in[1];
  const float* Wq  = (const float*)d_in[2];
  const float* bq  = (const float*)d_in[3];
  const float* Wv  = (const float*)d_in[4];
  const float* bv  = (const float*)d_in[5];
  const float* Wo  = (const float*)d_in[6];
  const float* bo  = (const float*)d_in[7];
  const float* W1  = (const float*)d_in[8];
  const float* b1  = (const float*)d_in[9];
  const float* W2  = (const float*)d_in[10];
  const float* b2  = (const float*)d_in[11];
  const float* g1  = (const float*)d_in[12];
  const float* be1 = (const float*)d_in[13];
  const float* g2  = (const float*)d_in[14];
  const float* be2 = (const float*)d_in[15];
  float* out = (float*)d_out;
  char* ws = (char*)d_ws;

  const int NT = B_ * S_;                       // 4096
  const size_t MB = 1024 * 1024;

  // workspace layout (bytes); h overlays [0, 16MB) (xb/qb/kvb/ctxb dead by then)
  short* xb   = (short*)(ws + 0 * MB);          // 4 MB
  short* qb   = (short*)(ws + 4 * MB);          // 4 MB
  short* kvb  = (short*)(ws + 8 * MB);          // 4 MB
  short* ctxb = (short*)(ws + 12 * MB);         // 4 MB
  short* h    = (short*)(ws + 0 * MB);          // 16 MB (overlay)
  short* WqT  = (short*)(ws + 16 * MB);         // 0.5 MB
  short* WvT  = (short*)(ws + 16 * MB + 512 * 1024);
  short* WoT  = (short*)(ws + 17 * MB);
  short* W1T  = (short*)(ws + 17 * MB + 512 * 1024);  // 2 MB
  short* W2T  = (short*)(ws + 19 * MB + 512 * 1024);  // 2 MB
  float* y    = (float*)(ws + 21 * MB + 512 * 1024);  // 8 MB
  float* x1   = (float*)(ws + 29 * MB + 512 * 1024);  // 8 MB
  short* x1b  = (short*)(ws + 37 * MB + 512 * 1024);  // 4 MB
  float* y2   = (float*)(ws + 41 * MB + 512 * 1024);  // 8 MB

  const dim3 blk(256);

  // prep: x -> bf16 ; weights -> bf16 transposed [N][K]
  f2b_kernel<<<dim3((NT * E_) / 1024), blk, 0, stream>>>(x, xb, NT * E_);
  transpose_b_kernel<<<dim3(E_ / 32, E_ / 32), blk, 0, stream>>>(Wq, WqT, E_, E_);
  transpose_b_kernel<<<dim3(E_ / 32, E_ / 32), blk, 0, stream>>>(Wv, WvT, E_, E_);
  transpose_b_kernel<<<dim3(E_ / 32, E_ / 32), blk, 0, stream>>>(Wo, WoT, E_, E_);
  transpose_b_kernel<<<dim3(F_ / 32, E_ / 32), blk, 0, stream>>>(W1, W1T, E_, F_);
  transpose_b_kernel<<<dim3(E_ / 32, F_ / 32), blk, 0, stream>>>(W2, W2T, F_, E_);

  // q = x@Wq+bq ; kv = x@Wv+bv  (bf16 outputs)
  mfma_gemm_kernel<<<dim3(E_ / 128, NT / 128), blk, 0, stream>>>(
      xb, WqT, bq, nullptr, qb, NT, E_, E_, 0);
  mfma_gemm_kernel<<<dim3(E_ / 128, NT / 128), blk, 0, stream>>>(
      xb, WvT, bv, nullptr, kvb, NT, E_, E_, 0);

  // ctx = softmax(q kv^T / 8 + bias) @ kv   (bf16 out)
  attn_mfma_kernel<<<dim3(S_ / 64, H_, B_), blk, 0, stream>>>(qb, kvb, bia, ctxb);

  // y = ctx@Wo+bo (fp32) ; x1 = x + LN(y) (fp32 + bf16)
  mfma_gemm_kernel<<<dim3(E_ / 128, NT / 128), blk, 0, stream>>>(
      ctxb, WoT, bo, y, nullptr, NT, E_, E_, 0);
  add_ln_kernel<<<dim3(NT), blk, 0, stream>>>(x, y, g1, be1, x1, x1b);

  // h = gelu(x1@W1+b1) (bf16) ; y2 = h@W2+b2 (fp32) ; out = x1 + LN(y2)
  mfma_gemm_kernel<<<dim3(F_ / 128, NT / 128), blk, 0, stream>>>(
      x1b, W1T, b1, nullptr, h, NT, F_, E_, 1);
  mfma_gemm_kernel<<<dim3(E_ / 128, NT / 128), blk, 0, stream>>>(
      h, W2T, b2, y2, nullptr, NT, E_, F_, 0);
  add_ln_kernel<<<dim3(NT), blk, 0, stream>>>(x1, y2, g2, be2, out, nullptr);
}

// Round 5
// 354.738 us; speedup vs baseline: 2.0880x; 1.1570x over previous
//
#include <hip/hip_runtime.h>
#include <cstddef>
#include <cstdint>

#define B_ 4
#define S_ 1024
#define E_ 512
#define H_ 8
#define F_ 2048
// DK=64, scale=1/8; token pitch of fused qkv buffer:
#define QKV_P 1024

typedef __attribute__((ext_vector_type(8))) short s16x8;
typedef __attribute__((ext_vector_type(4))) short s16x4;
typedef __attribute__((ext_vector_type(4))) float f32x4;

static __device__ __forceinline__ short f2bf(float f) {
  union { float f; unsigned u; } x; x.f = f;
  unsigned r = x.u + 0x7fffu + ((x.u >> 16) & 1u);   // RNE
  return (short)(r >> 16);
}

static __device__ __forceinline__ void gload_lds16(const void* g, void* l) {
  __builtin_amdgcn_global_load_lds(
      (const __attribute__((address_space(1))) void*)g,
      (__attribute__((address_space(3))) void*)l, 16, 0, 0);
}

// ---------------------------------------------------------------------------
// x fp32 -> bf16
// ---------------------------------------------------------------------------
__global__ __launch_bounds__(256) void f2b_kernel(const float* __restrict__ in,
                                                  short* __restrict__ out, int n) {
  int i = (blockIdx.x * 256 + threadIdx.x) * 4;
  if (i >= n) return;
  const float4 v = *(const float4*)&in[i];
  s16x4 o = { f2bf(v.x), f2bf(v.y), f2bf(v.z), f2bf(v.w) };
  *(s16x4*)&out[i] = o;
}

// ---------------------------------------------------------------------------
// One dispatch: all 5 weight transposes (fp32 [K][N] -> bf16 [N][K]) + bias
// concat bqv = [bq|bv].  Block ranges: Wq 256, Wv 256, Wo 256, W1 1024,
// W2 1024, bias 1.  Branch is block-uniform.
// ---------------------------------------------------------------------------
__global__ __launch_bounds__(256) void prep_weights_kernel(
    const float* __restrict__ Wq, const float* __restrict__ Wv,
    const float* __restrict__ Wo, const float* __restrict__ W1,
    const float* __restrict__ W2, const float* __restrict__ bq,
    const float* __restrict__ bv, short* __restrict__ WqvT,
    short* __restrict__ WoT, short* __restrict__ W1T, short* __restrict__ W2T,
    float* __restrict__ bqv)
{
  const int bid = blockIdx.x;
  const float* src; short* dst; int K, N, lb;
  if (bid < 256)       { src = Wq; dst = WqvT;             K = 512;  N = 512;  lb = bid; }
  else if (bid < 512)  { src = Wv; dst = WqvT + 512 * 512; K = 512;  N = 512;  lb = bid - 256; }
  else if (bid < 768)  { src = Wo; dst = WoT;              K = 512;  N = 512;  lb = bid - 512; }
  else if (bid < 1792) { src = W1; dst = W1T;              K = 512;  N = 2048; lb = bid - 768; }
  else if (bid < 2816) { src = W2; dst = W2T;              K = 2048; N = 512;  lb = bid - 1792; }
  else {
    const int i = threadIdx.x * 4;
    float4 v = (i < 512) ? *(const float4*)&bq[i] : *(const float4*)&bv[i - 512];
    *(float4*)&bqv[i] = v;
    return;
  }
  const int nbx = N / 32;
  const int bx = (lb % nbx) * 32, by = (lb / nbx) * 32;
  __shared__ float tile[32][33];
  const int tx = threadIdx.x & 31, ty = threadIdx.x >> 5;
  #pragma unroll
  for (int i = ty; i < 32; i += 8)
    tile[i][tx] = src[(size_t)(by + i) * N + bx + tx];
  __syncthreads();
  #pragma unroll
  for (int i = ty; i < 32; i += 8)
    dst[(size_t)(bx + i) * K + by + tx] = f2bf(tile[tx][i]);
}

// ---------------------------------------------------------------------------
// MFMA GEMM, tile BMxBN (m97 structure), BK=32, 256 thr = 4 waves (2x2).
// A bf16 [M][K], Bt bf16 [N][K].  ACT: 1 = exact GELU.  OUTF: 1 = fp32 out.
// ---------------------------------------------------------------------------
template<int BM, int BN, int ACT, int OUTF>
__global__ __launch_bounds__(256) void gemm_t(
    const short* __restrict__ A, const short* __restrict__ Bt,
    const float* __restrict__ bias, float* __restrict__ Cf,
    short* __restrict__ Cb, int M, int N, int K)
{
  constexpr int MR = BM / 32;   // M fragments per wave
  constexpr int NR = BN / 32;   // N fragments per wave
  __shared__ __align__(16) short As[BM * 32];
  __shared__ __align__(16) short Bs[BN * 32];

  const int t = threadIdx.x;
  const int w = t >> 6, lane = t & 63;
  const int wr = w >> 1, wc = w & 1;
  const int lr = lane & 15, lg = lane >> 4;
  const int bm = blockIdx.y * BM, bn = blockIdx.x * BN;
  const int srow = t >> 2, skcol = (t & 3) * 8;

  f32x4 acc[MR][NR] = {};

  for (int k0 = 0; k0 < K; k0 += 32) {
    #pragma unroll
    for (int i = 0; i < BM / 64; ++i)
      gload_lds16(&A[(size_t)(bm + i * 64 + srow) * K + k0 + skcol], &As[i * 2048 + t * 8]);
    #pragma unroll
    for (int i = 0; i < BN / 64; ++i)
      gload_lds16(&Bt[(size_t)(bn + i * 64 + srow) * K + k0 + skcol], &Bs[i * 2048 + t * 8]);
    __syncthreads();

    s16x8 af[MR], bf[NR];
    #pragma unroll
    for (int m = 0; m < MR; ++m)
      af[m] = *(const s16x8*)&As[(wr * (BM / 2) + m * 16 + lr) * 32 + lg * 8];
    #pragma unroll
    for (int n = 0; n < NR; ++n)
      bf[n] = *(const s16x8*)&Bs[(wc * (BN / 2) + n * 16 + lr) * 32 + lg * 8];
    #pragma unroll
    for (int m = 0; m < MR; ++m)
      #pragma unroll
      for (int n = 0; n < NR; ++n)
        acc[m][n] = __builtin_amdgcn_mfma_f32_16x16x32_bf16(af[m], bf[n], acc[m][n], 0, 0, 0);
    __syncthreads();
  }

  #pragma unroll
  for (int m = 0; m < MR; ++m) {
    #pragma unroll
    for (int n = 0; n < NR; ++n) {
      const int col = bn + wc * (BN / 2) + n * 16 + lr;
      const float bb = bias[col];
      #pragma unroll
      for (int r = 0; r < 4; ++r) {
        const int row = bm + wr * (BM / 2) + m * 16 + lg * 4 + r;
        float v = acc[m][n][r] + bb;
        if (ACT == 1) v = 0.5f * v * (1.0f + erff(v * 0.70710678118654752f));
        if (OUTF) Cf[(size_t)row * N + col] = v;
        else      Cb[(size_t)row * N + col] = f2bf(v);
      }
    }
  }
}

// ---------------------------------------------------------------------------
// MFMA flash attention, 2-deep software pipeline (T14): K-frags/V/bias for
// tile kb+1 issued before computing tile kb.  QKV fused buffer pitch 1024
// (Q at col 0, KV at col 512).  bias fp32 streamed.  ctx bf16 pitch 512.
// ---------------------------------------------------------------------------
__global__ __launch_bounds__(256, 2) void attn_mfma_kernel(
    const short* __restrict__ QKV, const float* __restrict__ bias,
    short* __restrict__ Ctx)
{
  __shared__ __align__(16) short Vt[64 * 68];     // [d][kv]
  __shared__ __align__(16) short Pb[4][16 * 72];  // per-wave P [q16][kv64]

  const int t = threadIdx.x;
  const int w = t >> 6, lane = t & 63;
  const int lr = lane & 15, lg = lane >> 4;
  const int qt = blockIdx.x, h = blockIdx.y, b = blockIdx.z;

  // Q A-fragments direct from global
  s16x8 aq0, aq1;
  {
    const size_t qoff = (size_t)(b * S_ + qt * 64 + w * 16 + lr) * QKV_P + h * 64;
    aq0 = *(const s16x8*)&QKV[qoff + lg * 8];
    aq1 = *(const s16x8*)&QKV[qoff + 32 + lg * 8];
  }

  f32x4 o[4];
  #pragma unroll
  for (int n = 0; n < 4; ++n) o[n] = (f32x4){0.f, 0.f, 0.f, 0.f};
  float mst[4] = {-1e30f, -1e30f, -1e30f, -1e30f};
  float lst[4] = {0.f, 0.f, 0.f, 0.f};

  const int kv_r = t & 63;
  const int d0 = (t >> 6) * 16;

  // prefetch set A/B register buffers
  s16x8 bkA[4][2], bkB[4][2], vA0, vA1, vB0, vB1;
  float bbA[4][4], bbB[4][4];   // [r][n]

  auto loadset = [&](s16x8 (&bk)[4][2], s16x8& v0, s16x8& v1,
                     float (&bb)[4][4], int kb) {
    const size_t voff = (size_t)(b * S_ + kb * 64 + kv_r) * QKV_P + 512 + h * 64 + d0;
    v0 = *(const s16x8*)&QKV[voff];
    v1 = *(const s16x8*)&QKV[voff + 8];
    #pragma unroll
    for (int n = 0; n < 4; ++n) {
      const size_t koff = (size_t)(b * S_ + kb * 64 + n * 16 + lr) * QKV_P + 512 + h * 64;
      bk[n][0] = *(const s16x8*)&QKV[koff + lg * 8];
      bk[n][1] = *(const s16x8*)&QKV[koff + 32 + lg * 8];
    }
    #pragma unroll
    for (int r = 0; r < 4; ++r) {
      const size_t boff = (((size_t)(b * H_ + h)) * S_ + qt * 64 + w * 16 + lg * 4 + r) * S_
                        + kb * 64 + lr;
      #pragma unroll
      for (int n = 0; n < 4; ++n) bb[r][n] = bias[boff + n * 16];
    }
  };

  auto body = [&](s16x8 (&bk)[4][2], s16x8& v0, s16x8& v1, float (&bb)[4][4]) {
    __syncthreads();   // prev PV reads of Vt/Pb done
    #pragma unroll
    for (int i = 0; i < 8; ++i) Vt[(d0 + i) * 68 + kv_r] = v0[i];
    #pragma unroll
    for (int i = 0; i < 8; ++i) Vt[(d0 + 8 + i) * 68 + kv_r] = v1[i];

    f32x4 c[4];
    #pragma unroll
    for (int n = 0; n < 4; ++n) c[n] = (f32x4){0.f, 0.f, 0.f, 0.f};
    #pragma unroll
    for (int n = 0; n < 4; ++n)
      c[n] = __builtin_amdgcn_mfma_f32_16x16x32_bf16(aq0, bk[n][0], c[n], 0, 0, 0);
    #pragma unroll
    for (int n = 0; n < 4; ++n)
      c[n] = __builtin_amdgcn_mfma_f32_16x16x32_bf16(aq1, bk[n][1], c[n], 0, 0, 0);

    float p[4][4];   // [n][r]
    #pragma unroll
    for (int r = 0; r < 4; ++r)
      #pragma unroll
      for (int n = 0; n < 4; ++n)
        p[n][r] = c[n][r] * 0.125f + bb[r][n];

    #pragma unroll
    for (int r = 0; r < 4; ++r) {
      float rm = fmaxf(fmaxf(p[0][r], p[1][r]), fmaxf(p[2][r], p[3][r]));
      rm = fmaxf(rm, __shfl_xor(rm, 1));
      rm = fmaxf(rm, __shfl_xor(rm, 2));
      rm = fmaxf(rm, __shfl_xor(rm, 4));
      rm = fmaxf(rm, __shfl_xor(rm, 8));
      const float mnew = fmaxf(mst[r], rm);
      const float alpha = __expf(mst[r] - mnew);
      mst[r] = mnew;
      float rs = 0.f;
      #pragma unroll
      for (int n = 0; n < 4; ++n) { p[n][r] = __expf(p[n][r] - mnew); rs += p[n][r]; }
      rs += __shfl_xor(rs, 1);
      rs += __shfl_xor(rs, 2);
      rs += __shfl_xor(rs, 4);
      rs += __shfl_xor(rs, 8);
      lst[r] = lst[r] * alpha + rs;
      #pragma unroll
      for (int n = 0; n < 4; ++n) o[n][r] *= alpha;
      #pragma unroll
      for (int n = 0; n < 4; ++n)
        Pb[w][(lg * 4 + r) * 72 + n * 16 + lr] = f2bf(p[n][r]);
    }
    __syncthreads();   // Vt + Pb visible

    s16x8 pa0 = *(const s16x8*)&Pb[w][lr * 72 + lg * 8];
    s16x8 pa1 = *(const s16x8*)&Pb[w][lr * 72 + 32 + lg * 8];
    #pragma unroll
    for (int ks = 0; ks < 2; ++ks) {
      #pragma unroll
      for (int n = 0; n < 4; ++n) {
        const int off = (n * 16 + lr) * 68 + ks * 32 + lg * 8;
        const s16x4 lo = *(const s16x4*)&Vt[off];
        const s16x4 hi = *(const s16x4*)&Vt[off + 4];
        const s16x8 bv = {lo[0], lo[1], lo[2], lo[3], hi[0], hi[1], hi[2], hi[3]};
        o[n] = __builtin_amdgcn_mfma_f32_16x16x32_bf16(ks == 0 ? pa0 : pa1, bv, o[n], 0, 0, 0);
      }
    }
  };

  loadset(bkA, vA0, vA1, bbA, 0);
  for (int kb = 0; kb < S_ / 64; kb += 2) {
    if (kb + 1 < S_ / 64) loadset(bkB, vB0, vB1, bbB, kb + 1);
    body(bkA, vA0, vA1, bbA);
    if (kb + 2 < S_ / 64) loadset(bkA, vA0, vA1, bbA, kb + 2);
    body(bkB, vB0, vB1, bbB);
  }

  #pragma unroll
  for (int r = 0; r < 4; ++r) {
    const int qrow = qt * 64 + w * 16 + lg * 4 + r;
    const float inv = 1.0f / lst[r];
    #pragma unroll
    for (int n = 0; n < 4; ++n)
      Ctx[(size_t)(b * S_ + qrow) * E_ + h * 64 + n * 16 + lr] = f2bf(o[n][r] * inv);
  }
}

// ---------------------------------------------------------------------------
// out = xin + LayerNorm(y)*g + beta ; optional bf16 copy.
// ---------------------------------------------------------------------------
__global__ __launch_bounds__(256) void add_ln_kernel(
    const float* __restrict__ xin, const float* __restrict__ y,
    const float* __restrict__ g, const float* __restrict__ beta,
    float* __restrict__ out, short* __restrict__ outb)
{
  const int row = blockIdx.x;
  const int tid = threadIdx.x;
  const size_t base = (size_t)row * E_;

  const float2 v = *(const float2*)&y[base + tid * 2];
  float sum = v.x + v.y;
  float sq  = v.x * v.x + v.y * v.y;
  #pragma unroll
  for (int m = 32; m >= 1; m >>= 1) {
    sum += __shfl_xor(sum, m);
    sq  += __shfl_xor(sq, m);
  }
  __shared__ float rs[4], rq[4];
  const int wid = tid >> 6, lane = tid & 63;
  if (lane == 0) { rs[wid] = sum; rq[wid] = sq; }
  __syncthreads();
  sum = rs[0] + rs[1] + rs[2] + rs[3];
  sq  = rq[0] + rq[1] + rq[2] + rq[3];

  const float mu   = sum * (1.0f / E_);
  const float var  = sq * (1.0f / E_) - mu * mu;
  const float rstd = rsqrtf(var + 1e-5f);

  const float2 xv = *(const float2*)&xin[base + tid * 2];
  const float2 gv = *(const float2*)&g[tid * 2];
  const float2 bv = *(const float2*)&beta[tid * 2];
  float2 ov;
  ov.x = xv.x + (v.x - mu) * rstd * gv.x + bv.x;
  ov.y = xv.y + (v.y - mu) * rstd * gv.y + bv.y;
  *(float2*)&out[base + tid * 2] = ov;
  if (outb) {
    outb[base + tid * 2]     = f2bf(ov.x);
    outb[base + tid * 2 + 1] = f2bf(ov.y);
  }
}

// ---------------------------------------------------------------------------
extern "C" void kernel_launch(void* const* d_in, const int* in_sizes, int n_in,
                              void* d_out, int out_size, void* d_ws, size_t ws_size,
                              hipStream_t stream)
{
  const float* x   = (const float*)d_in[0];
  const float* bia = (const float*)d_in[1];
  const float* Wq  = (const float*)d_in[2];
  const float* bq  = (const float*)d_in[3];
  const float* Wv  = (const float*)d_in[4];
  const float* bv  = (const float*)d_in[5];
  const float* Wo  = (const float*)d_in[6];
  const float* bo  = (const float*)d_in[7];
  const float* W1  = (const float*)d_in[8];
  const float* b1  = (const float*)d_in[9];
  const float* W2  = (const float*)d_in[10];
  const float* b2  = (const float*)d_in[11];
  const float* g1  = (const float*)d_in[12];
  const float* be1 = (const float*)d_in[13];
  const float* g2  = (const float*)d_in[14];
  const float* be2 = (const float*)d_in[15];
  float* out = (float*)d_out;
  char* ws = (char*)d_ws;

  const int NT = B_ * S_;                       // 4096
  const size_t MB = 1024 * 1024;

  short* xb   = (short*)(ws + 0 * MB);          // 4 MB
  short* qkvb = (short*)(ws + 4 * MB);          // 8 MB  [4096][1024]
  short* ctxb = (short*)(ws + 12 * MB);         // 4 MB
  short* h    = (short*)(ws + 16 * MB);         // 16 MB [4096][2048]
  short* WqvT = (short*)(ws + 32 * MB);         // 1 MB  [1024][512]
  short* WoT  = (short*)(ws + 33 * MB);         // 0.5 MB
  short* W1T  = (short*)(ws + 34 * MB);         // 2 MB
  short* W2T  = (short*)(ws + 36 * MB);         // 2 MB
  float* bqv  = (float*)(ws + 38 * MB);         // 4 KB
  float* y    = (float*)(ws + 40 * MB);         // 8 MB
  float* x1   = (float*)(ws + 48 * MB);         // 8 MB
  short* x1b  = (short*)(ws + 56 * MB);         // 4 MB
  float* y2   = (float*)(ws + 60 * MB);         // 8 MB

  const dim3 blk(256);

  f2b_kernel<<<dim3((NT * E_) / 1024), blk, 0, stream>>>(x, xb, NT * E_);
  prep_weights_kernel<<<dim3(2817), blk, 0, stream>>>(
      Wq, Wv, Wo, W1, W2, bq, bv, WqvT, WoT, W1T, W2T, bqv);

  // qkv = x@[Wq|Wv] + [bq|bv]   (bf16, pitch 1024)
  gemm_t<128, 128, 0, 0><<<dim3(1024 / 128, NT / 128), blk, 0, stream>>>(
      xb, WqvT, bqv, nullptr, qkvb, NT, 1024, E_);

  // ctx = softmax(q kv^T / 8 + bias) @ kv
  attn_mfma_kernel<<<dim3(S_ / 64, H_, B_), blk, 0, stream>>>(qkvb, bia, ctxb);

  // y = ctx@Wo + bo (fp32) ; x1 = x + LN(y)
  gemm_t<64, 64, 0, 1><<<dim3(E_ / 64, NT / 64), blk, 0, stream>>>(
      ctxb, WoT, bo, y, nullptr, NT, E_, E_);
  add_ln_kernel<<<dim3(NT), blk, 0, stream>>>(x, y, g1, be1, x1, x1b);

  // h = gelu(x1@W1 + b1) (bf16) ; y2 = h@W2 + b2 (fp32) ; out = x1 + LN(y2)
  gemm_t<128, 128, 1, 0><<<dim3(F_ / 128, NT / 128), blk, 0, stream>>>(
      x1b, W1T, b1, nullptr, h, NT, F_, E_);
  gemm_t<64, 64, 0, 1><<<dim3(E_ / 64, NT / 64), blk, 0, stream>>>(
      h, W2T, b2, y2, nullptr, NT, E_, F_);
  add_ln_kernel<<<dim3(NT), blk, 0, stream>>>(x1, y2, g2, be2, out, nullptr);
}